// Round 3
// baseline (96.610 us; speedup 1.0000x reference)
//
#include <hip/hip_runtime.h>
#include <hip/hip_bf16.h>
#include <math.h>

// X: [32,3,256,256]; 8192 independent 16x16 patches (conv pad=1 zero-pads per
// patch). v4: TWO waves cooperate on one patch (halved per-wave latency,
// halved LDS per wave). Block = 256 threads = 4 waves = 2 patches.
// Both waves of a pair load the full patch (dup loads hit L2/L3), each packs
// half of the shared pair-slab (v2 layout: p2 = (x,x+1) bf16 pairs, px18 =
// (s,s+18) stripe pairs), one __syncthreads, then wave w convolves output
// rows w*8..w*8+7 (8 MFMA steps). Router logits exchanged via a tiny LDS
// buffer + one barrier; gates computed redundantly in both waves; both
// waves atomicAdd their half-patch contributions into Sy[32][8][4][4].
// Bias rides in MFMA C operands; router accumulator chained through C
// (each wave folds bias*8 so the pair totals bias*16).

typedef short bf16x8 __attribute__((ext_vector_type(8)));
typedef float f32x4 __attribute__((ext_vector_type(4)));

__device__ __forceinline__ int cellOf(int r) {
    int rr = r + 4;   // padded coordinate; cells of 66 in [0,264)
    return (rr >= 66) + (rr >= 132) + (rr >= 198);
}

__device__ __forceinline__ unsigned int packbf2(float lo, float hi) {
    __hip_bfloat162 h = __float22bfloat162_rn(make_float2(lo, hi));
    unsigned int u;
    __builtin_memcpy(&u, &h, 4);
    return u;
}

// ---------------- prep: zero Sy + build packed B + bias vectors ----------------
__global__ __launch_bounds__(256) void prep_kernel(
    const float* __restrict__ ew, const float* __restrict__ ebg,
    const float* __restrict__ pw, const float* __restrict__ pb,
    const float* __restrict__ keys, float* __restrict__ Sy,
    unsigned short* __restrict__ Bg, float* __restrict__ cbf)
{
    const int t = threadIdx.x;
    for (int i = t; i < 4096; i += 256) Sy[i] = 0.f;
    if (t < 72) {
        float sv[32];
        #pragma unroll
        for (int s = 0; s < 32; ++s) {
            int q, kx; bool zz = false;
            if (s < 16)       { q = s >> 1;  kx = s & 1; }
            else if (s < 18)  { q = 8;       kx = s - 16; }
            else if (s < 26)  { q = s - 18;  kx = 2; }
            else if (s == 26) { q = 8;       kx = 2; }
            else              { q = 0; kx = 0; zz = true; }
            const int ky = q / 3, c = q - ky * 3;
            const int widx = c * 9 + ky * 3 + kx;
            float a;
            if (t < 64) {
                a = ew[t * 27 + widx];
            } else {
                const int e = t - 64;
                a = 0.f;
                #pragma unroll
                for (int o = 0; o < 16; ++o)
                    a += keys[e * 16 + o] * pw[o * 27 + widx];
            }
            sv[s] = zz ? 0.f : a;
        }
        uint4 q0, q1, q2v, q3v;
        q0.x  = packbf2(sv[0],  sv[1]);  q0.y  = packbf2(sv[2],  sv[3]);
        q0.z  = packbf2(sv[4],  sv[5]);  q0.w  = packbf2(sv[6],  sv[7]);
        q1.x  = packbf2(sv[8],  sv[9]);  q1.y  = packbf2(sv[10], sv[11]);
        q1.z  = packbf2(sv[12], sv[13]); q1.w  = packbf2(sv[14], sv[15]);
        q2v.x = packbf2(sv[16], sv[17]); q2v.y = packbf2(sv[18], sv[19]);
        q2v.z = packbf2(sv[20], sv[21]); q2v.w = packbf2(sv[22], sv[23]);
        q3v.x = packbf2(sv[24], sv[25]); q3v.y = packbf2(sv[26], sv[27]);
        q3v.z = packbf2(sv[28], sv[29]); q3v.w = packbf2(sv[30], sv[31]);
        uint4* dst = reinterpret_cast<uint4*>(&Bg[t * 32]);
        dst[0] = q0; dst[1] = q1; dst[2] = q2v; dst[3] = q3v;
    }
    // bias vectors: cbf[0..63] = expert bias per channel; cbf[64..79] = router
    // bias per column (col j -> expert j&7)
    if (t >= 128 && t < 208) {
        const int i = t - 128;
        float c;
        if (i < 64) {
            c = ebg[i];
        } else {
            const int e = (i - 64) & 7;
            c = 0.f;
            #pragma unroll
            for (int o = 0; o < 16; ++o) c += keys[e * 16 + o] * pb[o];
        }
        cbf[i] = c;
    }
}

// one conv step: 4 aligned b32 pair-reads (base+imm), 5 MFMAs, relu accum.
// GEN=1 adds masked split accumulators; IM = wave-uniform i-split mask.
#define CONV_STEP(SB, GEN, IM) do {                                         \
    uint4 pkv_;                                                             \
    pkv_.x = base0[(SB)];                                                   \
    pkv_.y = base1[(SB)];                                                   \
    pkv_.z = base2[(SB)];                                                   \
    pkv_.w = base3[(SB)];                                                   \
    const bf16x8 afr_ = __builtin_bit_cast(bf16x8, pkv_);                   \
    const f32x4 a0_ = __builtin_amdgcn_mfma_f32_16x16x32_bf16(afr_, bfr0, cbv0, 0, 0, 0); \
    const f32x4 a1_ = __builtin_amdgcn_mfma_f32_16x16x32_bf16(afr_, bfr1, cbv1, 0, 0, 0); \
    const f32x4 a2_ = __builtin_amdgcn_mfma_f32_16x16x32_bf16(afr_, bfr2, cbv2, 0, 0, 0); \
    const f32x4 a3_ = __builtin_amdgcn_mfma_f32_16x16x32_bf16(afr_, bfr3, cbv3, 0, 0, 0); \
    a4acc = __builtin_amdgcn_mfma_f32_16x16x32_bf16(afr_, bfr4, a4acc, 0, 0, 0); \
    _Pragma("unroll")                                                       \
    for (int r = 0; r < 4; ++r) {                                           \
        const float m0 = fmaxf(a0_[r], 0.f);                                \
        const float m1 = fmaxf(a1_[r], 0.f);                                \
        const float m2 = fmaxf(a2_[r], 0.f);                                \
        const float m3 = fmaxf(a3_[r], 0.f);                                \
        pall[0] += m0; pall[1] += m1; pall[2] += m2; pall[3] += m3;         \
        if (GEN) {                                                          \
            const float mm0 = m0 * (IM), mm1 = m1 * (IM);                   \
            const float mm2 = m2 * (IM), mm3 = m3 * (IM);                   \
            pbot[0] += mm0; pbot[1] += mm1;                                 \
            pbot[2] += mm2; pbot[3] += mm3;                                 \
            pjb[0] = fmaf(m0, jmask[r], pjb[0]);                            \
            pjb[1] = fmaf(m1, jmask[r], pjb[1]);                            \
            pjb[2] = fmaf(m2, jmask[r], pjb[2]);                            \
            pjb[3] = fmaf(m3, jmask[r], pjb[3]);                            \
            pbjb[0] = fmaf(mm0, jmask[r], pbjb[0]);                         \
            pbjb[1] = fmaf(mm1, jmask[r], pbjb[1]);                         \
            pbjb[2] = fmaf(mm2, jmask[r], pbjb[2]);                         \
            pbjb[3] = fmaf(mm3, jmask[r], pbjb[3]);                         \
        }                                                                   \
    }                                                                       \
} while (0)

// softmax + gate from TOTAL logits in rsum (all 64 lanes; expert e = lid&7)
#define GATES_FROM_TOTAL()                                                  \
    float gv[4];                                                            \
    {                                                                       \
        float lg = rsum * (1.f / 256.f);                                    \
        float mx = fmaxf(lg, __shfl_xor(lg, 1));                            \
        mx = fmaxf(mx, __shfl_xor(mx, 2));                                  \
        mx = fmaxf(mx, __shfl_xor(mx, 4));                                  \
        float ex = __expf(lg - mx);                                         \
        float s = ex;                                                       \
        s += __shfl_xor(s, 1); s += __shfl_xor(s, 2); s += __shfl_xor(s, 4);\
        float sc = ex / s;                                                  \
        float g = sc / (1.f + __expf(-(sc - thr) * 10.f));                  \
        float gs = g;                                                       \
        gs += __shfl_xor(gs, 1); gs += __shfl_xor(gs, 2); gs += __shfl_xor(gs, 4); \
        float gn = g / (gs + 1e-9f);                                        \
        const int gb = (lid & 56);                                          \
        const int hb = (lid >> 3) & 1;                                      \
        gv[0] = __shfl(gn, gb | (0 + hb));                                  \
        gv[1] = __shfl(gn, gb | (2 + hb));                                  \
        gv[2] = __shfl(gn, gb | (4 + hb));                                  \
        gv[3] = __shfl(gn, gb | (6 + hb));                                  \
    }

// ---------------- fused expert+router conv + cell reduce ----------------
__global__ __launch_bounds__(256, 2) void fused_kernel(
    const float* __restrict__ X, const unsigned short* __restrict__ Bg,
    const float* __restrict__ thr_p, const float* __restrict__ cbf,
    float* __restrict__ Sy)
{
    // per-PATCH packed pair slabs (2 waves share one): p2 [0..976), px18 [976..1952)
    __shared__ __align__(16) unsigned int pk[2][1952];
    __shared__ float rsb[4][16];                  // per-wave router partials

    const int t = threadIdx.x;
    const int wid = t >> 6, lid = t & 63;
    const int r16 = lid & 15, kb = lid >> 4;
    const int pidl = wid >> 1;                    // patch slot in block (0/1)
    const int w = wid & 1;                        // half index (rows w*8..w*8+7)

    const int gp = (blockIdx.x << 1) | pidl;      // patch id 0..8191
    const int b = gp >> 8;
    const int pi = (gp >> 4) & 15, pj = gp & 15;
    const int rbase = pi << 4, cbase = pj << 4;

    unsigned int* pkw = pk[pidl];
    const float thr = thr_p[0];

    // ---- full-patch global loads (both waves of the pair; L2/L3 hits) ----
    const int lr = lid >> 2, lq = lid & 3;
    const float* xb = X + ((b * 3) << 16) + ((rbase + lr) << 8) + cbase + (lq << 2);
    const float4 c0 = *reinterpret_cast<const float4*>(xb);
    const float4 c1 = *reinterpret_cast<const float4*>(xb + 65536);
    const float4 c2 = *reinterpret_cast<const float4*>(xb + 131072);

    const bf16x8 bfr0 = *reinterpret_cast<const bf16x8*>(&Bg[(r16) * 32 + (kb << 3)]);
    const bf16x8 bfr1 = *reinterpret_cast<const bf16x8*>(&Bg[(16 + r16) * 32 + (kb << 3)]);
    const bf16x8 bfr2 = *reinterpret_cast<const bf16x8*>(&Bg[(32 + r16) * 32 + (kb << 3)]);
    const bf16x8 bfr3 = *reinterpret_cast<const bf16x8*>(&Bg[(48 + r16) * 32 + (kb << 3)]);
    const bf16x8 bfr4 = *reinterpret_cast<const bf16x8*>(&Bg[(64 + (r16 & 7)) * 32 + (kb << 3)]);

    const float cbs0 = cbf[r16];
    const float cbs1 = cbf[16 + r16];
    const float cbs2 = cbf[32 + r16];
    const float cbs3 = cbf[48 + r16];
    const float cbs4 = cbf[64 + r16];

    // ---- zero slab (wave w zeros its half), barrier, pack own rows ----
    {
        uint4* pk4 = reinterpret_cast<uint4*>(pkw);
        const uint4 z = make_uint4(0u, 0u, 0u, 0u);
        #pragma unroll
        for (int i = 0; i < 4; ++i) {
            const int rel = lid + (i << 6);
            if (rel < 244) pk4[w * 244 + rel] = z;
        }
    }
    __syncthreads();

    // neighbor values (all lanes participate; full patch in registers)
    float s0 = __shfl_up(c0.w, 1);
    float s1 = __shfl_up(c1.w, 1);
    float s2 = __shfl_up(c2.w, 1);
    const float c0p = (lq == 0) ? 0.f : s0;   // left neighbor / halo
    const float c1p = (lq == 0) ? 0.f : s1;
    const float c2p = (lq == 0) ? 0.f : s2;
    float nxx = __shfl_down(c0.x, 4);         // next row, channel 0
    float nxy = __shfl_down(c0.y, 4);
    float nxz = __shfl_down(c0.z, 4);
    float nxw = __shfl_down(c0.w, 4);
    if (lr == 15) { nxx = 0.f; nxy = 0.f; nxz = 0.f; nxw = 0.f; }

    if ((lr >> 3) == w) {                     // pack only this wave's rows
        const int y = lr + 1;
        const int b2 = y * 54 + (lq << 2);    // p2: pairs (col p, col p+1)
        unsigned int u0, u1, u2, u3;
        u0 = packbf2(c0p,  c0.x); u1 = packbf2(c0.x, c0.y);
        u2 = packbf2(c0.y, c0.z); u3 = packbf2(c0.z, c0.w);
        *reinterpret_cast<uint2*>(&pkw[b2])      = make_uint2(u0, u1);
        *reinterpret_cast<uint2*>(&pkw[b2 + 2])  = make_uint2(u2, u3);
        u0 = packbf2(c1p,  c1.x); u1 = packbf2(c1.x, c1.y);
        u2 = packbf2(c1.y, c1.z); u3 = packbf2(c1.z, c1.w);
        *reinterpret_cast<uint2*>(&pkw[b2 + 18]) = make_uint2(u0, u1);
        *reinterpret_cast<uint2*>(&pkw[b2 + 20]) = make_uint2(u2, u3);
        u0 = packbf2(c2p,  c2.x); u1 = packbf2(c2.x, c2.y);
        u2 = packbf2(c2.y, c2.z); u3 = packbf2(c2.z, c2.w);
        *reinterpret_cast<uint2*>(&pkw[b2 + 36]) = make_uint2(u0, u1);
        *reinterpret_cast<uint2*>(&pkw[b2 + 38]) = make_uint2(u2, u3);

        const int bx = 976 + y * 54 + (lq << 2);  // px18: (stripe, stripe+18)
        u0 = packbf2(c0.x, c1.x); u1 = packbf2(c0.y, c1.y);
        u2 = packbf2(c0.z, c1.z); u3 = packbf2(c0.w, c1.w);
        *reinterpret_cast<uint2*>(&pkw[bx])      = make_uint2(u0, u1);
        *reinterpret_cast<uint2*>(&pkw[bx + 2])  = make_uint2(u2, u3);
        u0 = packbf2(c1.x, c2.x); u1 = packbf2(c1.y, c2.y);
        u2 = packbf2(c1.z, c2.z); u3 = packbf2(c1.w, c2.w);
        *reinterpret_cast<uint2*>(&pkw[bx + 18]) = make_uint2(u0, u1);
        *reinterpret_cast<uint2*>(&pkw[bx + 20]) = make_uint2(u2, u3);
        u0 = packbf2(c2.x, nxx);  u1 = packbf2(c2.y, nxy);
        u2 = packbf2(c2.z, nxz);  u3 = packbf2(c2.w, nxw);
        *reinterpret_cast<uint2*>(&pkw[bx + 36]) = make_uint2(u0, u1);
        *reinterpret_cast<uint2*>(&pkw[bx + 38]) = make_uint2(u2, u3);

        if (lr == 0) {  // px18 halo row 0, c2 stripe pairs with real row-1 c0
            const int b0 = 976 + 36 + (lq << 2);
            u0 = packbf2(0.f, c0.x); u1 = packbf2(0.f, c0.y);
            u2 = packbf2(0.f, c0.z); u3 = packbf2(0.f, c0.w);
            *reinterpret_cast<uint2*>(&pkw[b0])     = make_uint2(u0, u1);
            *reinterpret_cast<uint2*>(&pkw[b0 + 2]) = make_uint2(u2, u3);
        }
    }
    __syncthreads();

    // ---- per-lane pair-read bases (v2 layout), pre-offset by w*8 rows ----
    int offp0, offp1, offp2, offp3;
    if (kb < 2) {                       // q0..q7 (kx0,kx1) pairs in p2
        const int t0 = kb * 72 + r16;
        offp0 = t0; offp1 = t0 + 18; offp2 = t0 + 36; offp3 = t0 + 54;
    } else if (kb == 2) {               // q8 pair in p2; q0/q2/q4 kx2 pairs in px18
        offp0 = 144 + r16; offp1 = 977 + r16; offp2 = 1013 + r16; offp3 = 1049 + r16;
    } else {                            // q6,q8 kx2 pairs in px18; slots 28..31 dead
        offp0 = 1085 + r16; offp1 = 1121 + r16; offp2 = 1121 + r16; offp3 = 1121 + r16;
    }
    const int w432 = w * 432;           // w*8 rows * 54
    const unsigned int* base0 = pkw + offp0 + w432;
    const unsigned int* base1 = pkw + offp1 + w432;
    const unsigned int* base2 = pkw + offp2 + w432;
    const unsigned int* base3 = pkw + offp3 + w432;

    const f32x4 cbv0 = {cbs0, cbs0, cbs0, cbs0};
    const f32x4 cbv1 = {cbs1, cbs1, cbs1, cbs1};
    const f32x4 cbv2 = {cbs2, cbs2, cbs2, cbs2};
    const f32x4 cbv3 = {cbs3, cbs3, cbs3, cbs3};
    const float rb8 = cbs4 * 8.f;       // router bias: 8 steps/wave (x2 waves = 16)
    f32x4 a4acc = {rb8, rb8, rb8, rb8};

    // ---- split geometry (wave-uniform) ----
    const int iA = cellOf(rbase), iB = cellOf(rbase + 15);
    const int jA = cellOf(cbase), jB = cellOf(cbase + 15);
    const int isp = (iA + 1) * 66 - 4 - rbase;    // <16 iff i-split
    const int jsp = (jA + 1) * 66 - 4 - cbase;    // <16 iff j-split
    const bool anySplit = (isp < 16) | (jsp < 16);
    const int w8 = w << 3;

    if (!anySplit) {
        // ================= lean path (75% of patches) =================
        float pall[4] = {0.f, 0.f, 0.f, 0.f};
        float pbot[4], pjb[4], pbjb[4], jmask[4];   // dead (GEN=0)
        (void)pbot; (void)pjb; (void)pbjb; (void)jmask;
        #pragma unroll
        for (int s = 0; s < 8; ++s) CONV_STEP(s * 54, 0, 0.f);

        float rsum = (a4acc[0] + a4acc[1]) + (a4acc[2] + a4acc[3]);
        rsum += __shfl_xor(rsum, 16);
        rsum += __shfl_xor(rsum, 32);
        if (lid < 16) rsb[wid][lid] = rsum;
        __syncthreads();
        rsum += rsb[wid ^ 1][r16];

        GATES_FROM_TOTAL();

        float tt = 0.f;
        #pragma unroll
        for (int nt = 0; nt < 4; ++nt) tt = fmaf(gv[nt], pall[nt], tt);
        tt += __shfl_xor(tt, 8);
        tt += __shfl_xor(tt, 16);
        tt += __shfl_xor(tt, 32);
        if (lid < 8)
            atomicAdd(&Sy[(b << 7) + (lid << 4) + iA * 4 + jA], tt);
    } else {
        // ================= generic split path (masked, unrolled) =======
        float jmask[4];
        #pragma unroll
        for (int r = 0; r < 4; ++r)
            jmask[r] = ((kb << 2) + r >= jsp) ? 1.f : 0.f;

        float pall[4] = {0.f, 0.f, 0.f, 0.f};
        float pbot[4] = {0.f, 0.f, 0.f, 0.f};
        float pjb[4]  = {0.f, 0.f, 0.f, 0.f};
        float pbjb[4] = {0.f, 0.f, 0.f, 0.f};
        #pragma unroll
        for (int s = 0; s < 8; ++s) {
            const float im = ((w8 + s) >= isp) ? 1.f : 0.f;   // bottom mask
            CONV_STEP(s * 54, 1, im);
        }

        float rsum = (a4acc[0] + a4acc[1]) + (a4acc[2] + a4acc[3]);
        rsum += __shfl_xor(rsum, 16);
        rsum += __shfl_xor(rsum, 32);
        if (lid < 16) rsb[wid][lid] = rsum;
        __syncthreads();
        rsum += rsb[wid ^ 1][r16];

        GATES_FROM_TOTAL();

        // top = all - bot; jB-side via jmask'd accumulators
        float tTA = 0.f, tTB = 0.f, tBA = 0.f, tBB = 0.f;
        #pragma unroll
        for (int nt = 0; nt < 4; ++nt) {
            tTA = fmaf(gv[nt], pall[nt] - pbot[nt], tTA);
            tTB = fmaf(gv[nt], pjb[nt] - pbjb[nt], tTB);
            tBA = fmaf(gv[nt], pbot[nt], tBA);
            tBB = fmaf(gv[nt], pbjb[nt], tBB);
        }
        #pragma unroll
        for (int m = 8; m <= 32; m <<= 1) {
            tTA += __shfl_xor(tTA, m);
            tTB += __shfl_xor(tTB, m);
            tBA += __shfl_xor(tBA, m);
            tBB += __shfl_xor(tBB, m);
        }
        if (lid < 8) {
            float* q = &Sy[(b << 7) + (lid << 4)];
            atomicAdd(&q[iA * 4 + jA], tTA - tTB);
            atomicAdd(&q[iA * 4 + jB], tTB);
            atomicAdd(&q[iB * 4 + jA], tBA - tBB);
            atomicAdd(&q[iB * 4 + jB], tBB);
        }
    }
}

// ---------------- SPP + head ----------------
__global__ __launch_bounds__(256) void head_kernel(
    const float* __restrict__ Sy, const float* __restrict__ fw,
    const float* __restrict__ fb, const float* __restrict__ lw,
    const float* __restrict__ lb, float* __restrict__ out)
{
    __shared__ float syl[128];
    __shared__ float s2[32];
    __shared__ float stot[8];
    __shared__ float spp[168];
    const int t = threadIdx.x;
    const int b = blockIdx.y;
    if (t < 128) syl[t] = Sy[b * 128 + t];
    __syncthreads();
    if (t < 32) {
        int c = t >> 2, I = (t >> 1) & 1, J = t & 1;
        const float* p = &syl[c * 16];
        s2[t] = p[(2 * I) * 4 + 2 * J] + p[(2 * I) * 4 + 2 * J + 1] +
                p[(2 * I + 1) * 4 + 2 * J] + p[(2 * I + 1) * 4 + 2 * J + 1];
    } else if (t >= 32 && t < 40) {
        int c = t - 32;
        float s = 0.f;
        #pragma unroll
        for (int i2 = 0; i2 < 16; ++i2) s += syl[c * 16 + i2];
        stot[c] = s;
    }
    __syncthreads();
    if (t < 168) {
        float acc = 0.f;
        int o;
        if (t < 8) {
            o = t;
            #pragma unroll
            for (int c = 0; c < 8; ++c) acc += fw[o * 8 + c] * stot[c];
            acc *= (1.f / 69696.f);
        } else if (t < 40) {
            int m = t - 8; o = m >> 2; int q = m & 3;
            #pragma unroll
            for (int c = 0; c < 8; ++c) acc += fw[o * 8 + c] * s2[c * 4 + q];
            acc *= (1.f / 17424.f);
        } else {
            int m = t - 40; o = m >> 4; int cell = m & 15;
            #pragma unroll
            for (int c = 0; c < 8; ++c) acc += fw[o * 8 + c] * syl[c * 16 + cell];
            acc *= (1.f / 4356.f);
        }
        spp[t] = acc + fb[o];
    }
    __syncthreads();
    const int n = blockIdx.x * 256 + t;
    if (n < 1000) {
        float acc = lb[n];
        for (int k = 0; k < 168; ++k) acc = fmaf(spp[k], lw[k * 1000 + n], acc);
        out[b * 1000 + n] = acc;
    }
}

extern "C" void kernel_launch(void* const* d_in, const int* in_sizes, int n_in,
                              void* d_out, int out_size, void* d_ws, size_t ws_size,
                              hipStream_t stream) {
    const float* X    = (const float*)d_in[0];
    const float* ew   = (const float*)d_in[1];
    const float* eb   = (const float*)d_in[2];
    const float* pw   = (const float*)d_in[3];
    const float* pb   = (const float*)d_in[4];
    const float* keys = (const float*)d_in[5];
    const float* thr  = (const float*)d_in[6];
    const float* fw   = (const float*)d_in[7];
    const float* fb   = (const float*)d_in[8];
    const float* lw   = (const float*)d_in[9];
    const float* lb   = (const float*)d_in[10];
    float* out = (float*)d_out;
    float* Sy  = (float*)d_ws;                                    // 4096 floats
    unsigned short* Bg = (unsigned short*)((float*)d_ws + 4096);  // 72*32 bf16
    float* cbf = (float*)d_ws + 5248;                             // 80 bias floats

    prep_kernel<<<1, 256, 0, stream>>>(ew, eb, pw, pb, keys, Sy, Bg, cbf);
    fused_kernel<<<4096, 256, 0, stream>>>(X, Bg, thr, cbf, Sy);
    head_kernel<<<dim3(4, 32), 256, 0, stream>>>(Sy, fw, fb, lw, lb, out);
}

// Round 4
// 39.162 us; speedup vs baseline: 2.4669x; 2.4669x over previous
//
#include <hip/hip_runtime.h>
#include <hip/hip_bf16.h>
#include <math.h>

// X: [32,3,256,256]; 8192 independent 16x16 patches (conv pad=1 zero-pads per
// patch). One wave = one patch, ZERO block-level syncs in the fused kernel.
//
// v5 = v2 kernel + TRANSPOSED Sy layout to kill atomic line contention.
// Old Sy[32][8][4][4]: one 64B line per (b,c) -> 256 lines x ~435 serialized
// device-atomic RMWs = the measured ~42us floor. New SyT[cell][b][16]
// (c0..7 + 8 pad): one line per (cell,b) -> 512 lines, <=~36 RMWs/line, and
// a wave's 8 c-lanes hit consecutive floats in ONE line (coalesced atomic).
//
// Inner loop (v2, proven): pre-packed bf16 PAIR slabs. p2 = pack(v,v+1) for
// (kx0,kx1) pairs, px18 = pack(v,v+18) for kx2 stripe pairs; B's k'' slot
// order matches (built in prep). Hot loop: 4 aligned ds_read_b32 -> 5 MFMAs.
// Bias rides in MFMA C operands; router accumulator chained through C.

typedef short bf16x8 __attribute__((ext_vector_type(8)));
typedef float f32x4 __attribute__((ext_vector_type(4)));

__device__ __forceinline__ int cellOf(int r) {
    int rr = r + 4;   // padded coordinate; cells of 66 in [0,264)
    return (rr >= 66) + (rr >= 132) + (rr >= 198);
}

__device__ __forceinline__ unsigned int packbf2(float lo, float hi) {
    __hip_bfloat162 h = __float22bfloat162_rn(make_float2(lo, hi));
    unsigned int u;
    __builtin_memcpy(&u, &h, 4);
    return u;
}

// ---------------- prep: zero SyT + build packed B + bias vectors ----------------
__global__ __launch_bounds__(256) void prep_kernel(
    const float* __restrict__ ew, const float* __restrict__ ebg,
    const float* __restrict__ pw, const float* __restrict__ pb,
    const float* __restrict__ keys, float* __restrict__ Sy,
    unsigned short* __restrict__ Bg, float* __restrict__ cbf)
{
    const int t = threadIdx.x;
    for (int i = t; i < 8192; i += 256) Sy[i] = 0.f;
    if (t < 72) {
        float sv[32];
        #pragma unroll
        for (int s = 0; s < 32; ++s) {
            int q, kx; bool zz = false;
            if (s < 16)       { q = s >> 1;  kx = s & 1; }
            else if (s < 18)  { q = 8;       kx = s - 16; }
            else if (s < 26)  { q = s - 18;  kx = 2; }
            else if (s == 26) { q = 8;       kx = 2; }
            else              { q = 0; kx = 0; zz = true; }
            const int ky = q / 3, c = q - ky * 3;
            const int widx = c * 9 + ky * 3 + kx;
            float a;
            if (t < 64) {
                a = ew[t * 27 + widx];
            } else {
                const int e = t - 64;
                a = 0.f;
                #pragma unroll
                for (int o = 0; o < 16; ++o)
                    a += keys[e * 16 + o] * pw[o * 27 + widx];
            }
            sv[s] = zz ? 0.f : a;
        }
        uint4 q0, q1, q2v, q3v;
        q0.x  = packbf2(sv[0],  sv[1]);  q0.y  = packbf2(sv[2],  sv[3]);
        q0.z  = packbf2(sv[4],  sv[5]);  q0.w  = packbf2(sv[6],  sv[7]);
        q1.x  = packbf2(sv[8],  sv[9]);  q1.y  = packbf2(sv[10], sv[11]);
        q1.z  = packbf2(sv[12], sv[13]); q1.w  = packbf2(sv[14], sv[15]);
        q2v.x = packbf2(sv[16], sv[17]); q2v.y = packbf2(sv[18], sv[19]);
        q2v.z = packbf2(sv[20], sv[21]); q2v.w = packbf2(sv[22], sv[23]);
        q3v.x = packbf2(sv[24], sv[25]); q3v.y = packbf2(sv[26], sv[27]);
        q3v.z = packbf2(sv[28], sv[29]); q3v.w = packbf2(sv[30], sv[31]);
        uint4* dst = reinterpret_cast<uint4*>(&Bg[t * 32]);
        dst[0] = q0; dst[1] = q1; dst[2] = q2v; dst[3] = q3v;
    }
    // bias vectors: cbf[0..63] = expert bias per channel; cbf[64..79] = router
    // bias per column (col j -> expert j&7)
    if (t >= 128 && t < 208) {
        const int i = t - 128;
        float c;
        if (i < 64) {
            c = ebg[i];
        } else {
            const int e = (i - 64) & 7;
            c = 0.f;
            #pragma unroll
            for (int o = 0; o < 16; ++o) c += keys[e * 16 + o] * pb[o];
        }
        cbf[i] = c;
    }
}

// one conv step: 4 aligned b32 pair-reads, 5 MFMAs, ungated relu accumulate.
#define CONV_STEP(SB, ACCJ) do {                                            \
    uint4 pkv;                                                              \
    pkv.x = pkw[offp0 + (SB)];                                              \
    pkv.y = pkw[offp1 + (SB)];                                              \
    pkv.z = pkw[offp2 + (SB)];                                              \
    pkv.w = pkw[offp3 + (SB)];                                              \
    const bf16x8 afr = __builtin_bit_cast(bf16x8, pkv);                     \
    const f32x4 a0 = __builtin_amdgcn_mfma_f32_16x16x32_bf16(afr, bfr0, cbv0, 0, 0, 0); \
    const f32x4 a1 = __builtin_amdgcn_mfma_f32_16x16x32_bf16(afr, bfr1, cbv1, 0, 0, 0); \
    const f32x4 a2 = __builtin_amdgcn_mfma_f32_16x16x32_bf16(afr, bfr2, cbv2, 0, 0, 0); \
    const f32x4 a3 = __builtin_amdgcn_mfma_f32_16x16x32_bf16(afr, bfr3, cbv3, 0, 0, 0); \
    a4acc = __builtin_amdgcn_mfma_f32_16x16x32_bf16(afr, bfr4, a4acc, 0, 0, 0); \
    _Pragma("unroll")                                                       \
    for (int r = 0; r < 4; ++r) {                                           \
        const float m0 = fmaxf(a0[r], 0.f);                                 \
        const float m1 = fmaxf(a1[r], 0.f);                                 \
        const float m2 = fmaxf(a2[r], 0.f);                                 \
        const float m3 = fmaxf(a3[r], 0.f);                                 \
        pall[0] += m0; pall[1] += m1; pall[2] += m2; pall[3] += m3;         \
        if (ACCJ) {                                                         \
            psb[0] = fmaf(m0, jmask[r], psb[0]);                            \
            psb[1] = fmaf(m1, jmask[r], psb[1]);                            \
            psb[2] = fmaf(m2, jmask[r], psb[2]);                            \
            psb[3] = fmaf(m3, jmask[r], psb[3]);                            \
        }                                                                   \
    }                                                                       \
} while (0)

// softmax + gate (all 64 lanes; lane's expert e = lid&7)
#define GATES_FROM_RSUM()                                                   \
    rsum += __shfl_xor(rsum, 16);                                           \
    rsum += __shfl_xor(rsum, 32);                                           \
    float gv[4];                                                            \
    {                                                                       \
        float lg = rsum * (1.f / 256.f);                                    \
        float mx = fmaxf(lg, __shfl_xor(lg, 1));                            \
        mx = fmaxf(mx, __shfl_xor(mx, 2));                                  \
        mx = fmaxf(mx, __shfl_xor(mx, 4));                                  \
        float ex = __expf(lg - mx);                                         \
        float s = ex;                                                       \
        s += __shfl_xor(s, 1); s += __shfl_xor(s, 2); s += __shfl_xor(s, 4);\
        float sc = ex / s;                                                  \
        float g = sc / (1.f + __expf(-(sc - thr) * 10.f));                  \
        float gs = g;                                                       \
        gs += __shfl_xor(gs, 1); gs += __shfl_xor(gs, 2); gs += __shfl_xor(gs, 4); \
        float gn = g / (gs + 1e-9f);                                        \
        const int gb = (lid & 56);                                          \
        const int hb = (lid >> 3) & 1;                                      \
        gv[0] = __shfl(gn, gb | (0 + hb));                                  \
        gv[1] = __shfl(gn, gb | (2 + hb));                                  \
        gv[2] = __shfl(gn, gb | (4 + hb));                                  \
        gv[3] = __shfl(gn, gb | (6 + hb));                                  \
    }

// ---------------- fused expert+router conv + cell reduce ----------------
__global__ __launch_bounds__(256, 4) void fused_kernel(
    const float* __restrict__ X, const unsigned short* __restrict__ Bg,
    const float* __restrict__ thr_p, const float* __restrict__ cbf,
    float* __restrict__ Sy)
{
    // per-wave packed pair slabs: p2 at [0..976), px18 stored at 976+i
    __shared__ __align__(16) unsigned int pk[4][1952];

    const int t = threadIdx.x;
    const int wid = t >> 6, lid = t & 63;
    const int r16 = lid & 15, kb = lid >> 4;

    const int gp = (blockIdx.x << 2) + wid;       // patch id 0..8191
    const int b = gp >> 8;
    const int pi = (gp >> 4) & 15, pj = gp & 15;
    const int rbase = pi << 4, cbase = pj << 4;

    unsigned int* pkw = pk[wid];
    const float thr = thr_p[0];

    // ---- issue all global loads up front (in flight together) ----
    const int lr = lid >> 2, lq = lid & 3;
    const float* xb = X + ((b * 3) << 16) + ((rbase + lr) << 8) + cbase + (lq << 2);
    const float4 xv0 = *reinterpret_cast<const float4*>(xb);
    const float4 xv1 = *reinterpret_cast<const float4*>(xb + 65536);
    const float4 xv2 = *reinterpret_cast<const float4*>(xb + 131072);

    const bf16x8 bfr0 = *reinterpret_cast<const bf16x8*>(&Bg[(r16) * 32 + (kb << 3)]);
    const bf16x8 bfr1 = *reinterpret_cast<const bf16x8*>(&Bg[(16 + r16) * 32 + (kb << 3)]);
    const bf16x8 bfr2 = *reinterpret_cast<const bf16x8*>(&Bg[(32 + r16) * 32 + (kb << 3)]);
    const bf16x8 bfr3 = *reinterpret_cast<const bf16x8*>(&Bg[(48 + r16) * 32 + (kb << 3)]);
    const bf16x8 bfr4 = *reinterpret_cast<const bf16x8*>(&Bg[(64 + (r16 & 7)) * 32 + (kb << 3)]);

    const float cbs0 = cbf[r16];
    const float cbs1 = cbf[16 + r16];
    const float cbs2 = cbf[32 + r16];
    const float cbs3 = cbf[48 + r16];
    const float cbs4 = cbf[64 + r16];

    // ---- zero the packed region (covers halo rows/cols; wave-private) ----
    {
        uint4* pk4 = reinterpret_cast<uint4*>(pkw);
        const uint4 z = make_uint4(0u, 0u, 0u, 0u);
        #pragma unroll
        for (int i = 0; i < 8; ++i) {
            const int idx = lid + (i << 6);
            if (idx < 488) pk4[idx] = z;
        }
    }
    __builtin_amdgcn_wave_barrier();

    // ---- build packed pair slabs straight from registers ----
    // lane owns input row lr (slab y = lr+1), slab cols 4lq+1..4lq+4, 3 chans.
    float s0 = __shfl_up(xv0.w, 1);
    float s1 = __shfl_up(xv1.w, 1);
    float s2 = __shfl_up(xv2.w, 1);
    const float c0p = (lq == 0) ? 0.f : s0;   // col 4lq (left neighbor / halo)
    const float c1p = (lq == 0) ? 0.f : s1;
    const float c2p = (lq == 0) ? 0.f : s2;
    float nxx = __shfl_down(xv0.x, 4);        // next row, channel 0 (for px c2)
    float nxy = __shfl_down(xv0.y, 4);
    float nxz = __shfl_down(xv0.z, 4);
    float nxw = __shfl_down(xv0.w, 4);
    if (lr == 15) { nxx = 0.f; nxy = 0.f; nxz = 0.f; nxw = 0.f; }

    {
        const int y = lr + 1;
        const int b2 = y * 54 + (lq << 2);            // p2: pairs (col p, col p+1)
        unsigned int u0, u1, u2, u3;
        u0 = packbf2(c0p,   xv0.x); u1 = packbf2(xv0.x, xv0.y);
        u2 = packbf2(xv0.y, xv0.z); u3 = packbf2(xv0.z, xv0.w);
        *reinterpret_cast<uint2*>(&pkw[b2])      = make_uint2(u0, u1);
        *reinterpret_cast<uint2*>(&pkw[b2 + 2])  = make_uint2(u2, u3);
        u0 = packbf2(c1p,   xv1.x); u1 = packbf2(xv1.x, xv1.y);
        u2 = packbf2(xv1.y, xv1.z); u3 = packbf2(xv1.z, xv1.w);
        *reinterpret_cast<uint2*>(&pkw[b2 + 18]) = make_uint2(u0, u1);
        *reinterpret_cast<uint2*>(&pkw[b2 + 20]) = make_uint2(u2, u3);
        u0 = packbf2(c2p,   xv2.x); u1 = packbf2(xv2.x, xv2.y);
        u2 = packbf2(xv2.y, xv2.z); u3 = packbf2(xv2.z, xv2.w);
        *reinterpret_cast<uint2*>(&pkw[b2 + 36]) = make_uint2(u0, u1);
        *reinterpret_cast<uint2*>(&pkw[b2 + 38]) = make_uint2(u2, u3);

        const int bx = 976 + y * 54 + (lq << 2);      // px18: pairs (stripe, stripe+18)
        u0 = packbf2(xv0.x, xv1.x); u1 = packbf2(xv0.y, xv1.y);
        u2 = packbf2(xv0.z, xv1.z); u3 = packbf2(xv0.w, xv1.w);
        *reinterpret_cast<uint2*>(&pkw[bx])      = make_uint2(u0, u1);
        *reinterpret_cast<uint2*>(&pkw[bx + 2])  = make_uint2(u2, u3);
        u0 = packbf2(xv1.x, xv2.x); u1 = packbf2(xv1.y, xv2.y);
        u2 = packbf2(xv1.z, xv2.z); u3 = packbf2(xv1.w, xv2.w);
        *reinterpret_cast<uint2*>(&pkw[bx + 18]) = make_uint2(u0, u1);
        *reinterpret_cast<uint2*>(&pkw[bx + 20]) = make_uint2(u2, u3);
        u0 = packbf2(xv2.x, nxx);  u1 = packbf2(xv2.y, nxy);
        u2 = packbf2(xv2.z, nxz);  u3 = packbf2(xv2.w, nxw);
        *reinterpret_cast<uint2*>(&pkw[bx + 36]) = make_uint2(u0, u1);
        *reinterpret_cast<uint2*>(&pkw[bx + 38]) = make_uint2(u2, u3);

        if (lr == 0) {  // px18 halo row 0, c2 stripe pairs with real row-1 c0
            const int b0 = 976 + 36 + (lq << 2);
            u0 = packbf2(0.f, xv0.x); u1 = packbf2(0.f, xv0.y);
            u2 = packbf2(0.f, xv0.z); u3 = packbf2(0.f, xv0.w);
            *reinterpret_cast<uint2*>(&pkw[b0])     = make_uint2(u0, u1);
            *reinterpret_cast<uint2*>(&pkw[b0 + 2]) = make_uint2(u2, u3);
        }
    }
    __builtin_amdgcn_wave_barrier();

    // ---- per-lane pair-read offsets (dwords); +mt*54 in loop, folded to imm ----
    int offp0, offp1, offp2, offp3;
    if (kb < 2) {                       // q0..q7 (kx0,kx1) pairs in p2
        const int t0 = kb * 72 + r16;
        offp0 = t0; offp1 = t0 + 18; offp2 = t0 + 36; offp3 = t0 + 54;
    } else if (kb == 2) {               // q8 pair in p2; q0/q2/q4 kx2 pairs in px18
        offp0 = 144 + r16; offp1 = 977 + r16; offp2 = 1013 + r16; offp3 = 1049 + r16;
    } else {                            // q6,q8 kx2 pairs in px18; slots 28..31 dead
        offp0 = 1085 + r16; offp1 = 1121 + r16; offp2 = 1121 + r16; offp3 = 1121 + r16;
    }

    const f32x4 cbv0 = {cbs0, cbs0, cbs0, cbs0};
    const f32x4 cbv1 = {cbs1, cbs1, cbs1, cbs1};
    const f32x4 cbv2 = {cbs2, cbs2, cbs2, cbs2};
    const f32x4 cbv3 = {cbs3, cbs3, cbs3, cbs3};
    const float rb16 = cbs4 * 16.f;     // router bias: 16 steps fold into C init
    f32x4 a4acc = {rb16, rb16, rb16, rb16};

    // ---- split geometry (wave-uniform) ----
    const int iA = cellOf(rbase), iB = cellOf(rbase + 15);
    const int jA = cellOf(cbase), jB = cellOf(cbase + 15);
    const int isp = (iA + 1) * 66 - 4 - rbase;    // <16 iff i-split
    const int jsp = (jA + 1) * 66 - 4 - cbase;    // <16 iff j-split
    const bool anySplit = (isp < 16) | (jsp < 16);

    const int bc16 = b << 4;            // SyT[cell][b][16]: line-sized groups

    if (!anySplit) {
        // ================= lean path (75% of patches) =================
        float pall[4] = {0.f, 0.f, 0.f, 0.f};
        float psb[4]  = {0.f, 0.f, 0.f, 0.f};     // dead (ACCJ=0)
        float jmask[4] = {0.f, 0.f, 0.f, 0.f};    // dead
        #pragma unroll
        for (int mt = 0; mt < 16; ++mt) CONV_STEP(mt * 54, 0);

        float rsum = (a4acc[0] + a4acc[1]) + (a4acc[2] + a4acc[3]);
        GATES_FROM_RSUM();

        float tt = 0.f;
        #pragma unroll
        for (int nt = 0; nt < 4; ++nt) tt = fmaf(gv[nt], pall[nt], tt);
        tt += __shfl_xor(tt, 8);
        tt += __shfl_xor(tt, 16);
        tt += __shfl_xor(tt, 32);
        if (lid < 8)
            atomicAdd(&Sy[(iA * 4 + jA) * 512 + bc16 + lid], tt);
    } else {
        // ================= generic split path =================
        float jmask[4];
        #pragma unroll
        for (int r = 0; r < 4; ++r)
            jmask[r] = ((kb << 2) + r >= jsp) ? 1.f : 0.f;

        float pall[4] = {0.f, 0.f, 0.f, 0.f};
        float psb[4]  = {0.f, 0.f, 0.f, 0.f};
        const int m1 = isp < 16 ? isp : 16;

        int sb = 0;
        for (int mt = 0; mt < m1; ++mt) { CONV_STEP(sb, 1); sb += 54; }
        const float pa0_0 = pall[0], pa0_1 = pall[1], pa0_2 = pall[2], pa0_3 = pall[3];
        const float pb0_0 = psb[0],  pb0_1 = psb[1],  pb0_2 = psb[2],  pb0_3 = psb[3];
        pall[0] = pall[1] = pall[2] = pall[3] = 0.f;
        psb[0] = psb[1] = psb[2] = psb[3] = 0.f;
        for (int mt = m1; mt < 16; ++mt) { CONV_STEP(sb, 1); sb += 54; }

        float rsum = (a4acc[0] + a4acc[1]) + (a4acc[2] + a4acc[3]);
        GATES_FROM_RSUM();

        float tTA = gv[0] * pa0_0 + gv[1] * pa0_1 + gv[2] * pa0_2 + gv[3] * pa0_3;
        float tTB = gv[0] * pb0_0 + gv[1] * pb0_1 + gv[2] * pb0_2 + gv[3] * pb0_3;
        float tBA = gv[0] * pall[0] + gv[1] * pall[1] + gv[2] * pall[2] + gv[3] * pall[3];
        float tBB = gv[0] * psb[0] + gv[1] * psb[1] + gv[2] * psb[2] + gv[3] * psb[3];
        #pragma unroll
        for (int m = 8; m <= 32; m <<= 1) {
            tTA += __shfl_xor(tTA, m);
            tTB += __shfl_xor(tTB, m);
            tBA += __shfl_xor(tBA, m);
            tBB += __shfl_xor(tBB, m);
        }
        if (lid < 8) {
            atomicAdd(&Sy[(iA * 4 + jA) * 512 + bc16 + lid], tTA - tTB);
            atomicAdd(&Sy[(iA * 4 + jB) * 512 + bc16 + lid], tTB);
            atomicAdd(&Sy[(iB * 4 + jA) * 512 + bc16 + lid], tBA - tBB);
            atomicAdd(&Sy[(iB * 4 + jB) * 512 + bc16 + lid], tBB);
        }
    }
}

// ---------------- SPP + head ----------------
__global__ __launch_bounds__(256) void head_kernel(
    const float* __restrict__ Sy, const float* __restrict__ fw,
    const float* __restrict__ fb, const float* __restrict__ lw,
    const float* __restrict__ lb, float* __restrict__ out)
{
    __shared__ float syl[128];
    __shared__ float s2[32];
    __shared__ float stot[8];
    __shared__ float spp[168];
    const int t = threadIdx.x;
    const int b = blockIdx.y;
    // SyT[cell][b][16]: syl[c*16+cell] = SyT[cell*512 + b*16 + c]
    if (t < 128) syl[t] = Sy[(t & 15) * 512 + b * 16 + (t >> 4)];
    __syncthreads();
    if (t < 32) {
        int c = t >> 2, I = (t >> 1) & 1, J = t & 1;
        const float* p = &syl[c * 16];
        s2[t] = p[(2 * I) * 4 + 2 * J] + p[(2 * I) * 4 + 2 * J + 1] +
                p[(2 * I + 1) * 4 + 2 * J] + p[(2 * I + 1) * 4 + 2 * J + 1];
    } else if (t >= 32 && t < 40) {
        int c = t - 32;
        float s = 0.f;
        #pragma unroll
        for (int i2 = 0; i2 < 16; ++i2) s += syl[c * 16 + i2];
        stot[c] = s;
    }
    __syncthreads();
    if (t < 168) {
        float acc = 0.f;
        int o;
        if (t < 8) {
            o = t;
            #pragma unroll
            for (int c = 0; c < 8; ++c) acc += fw[o * 8 + c] * stot[c];
            acc *= (1.f / 69696.f);
        } else if (t < 40) {
            int m = t - 8; o = m >> 2; int q = m & 3;
            #pragma unroll
            for (int c = 0; c < 8; ++c) acc += fw[o * 8 + c] * s2[c * 4 + q];
            acc *= (1.f / 17424.f);
        } else {
            int m = t - 40; o = m >> 4; int cell = m & 15;
            #pragma unroll
            for (int c = 0; c < 8; ++c) acc += fw[o * 8 + c] * syl[c * 16 + cell];
            acc *= (1.f / 4356.f);
        }
        spp[t] = acc + fb[o];
    }
    __syncthreads();
    const int n = blockIdx.x * 256 + t;
    if (n < 1000) {
        float acc = lb[n];
        for (int k = 0; k < 168; ++k) acc = fmaf(spp[k], lw[k * 1000 + n], acc);
        out[b * 1000 + n] = acc;
    }
}

extern "C" void kernel_launch(void* const* d_in, const int* in_sizes, int n_in,
                              void* d_out, int out_size, void* d_ws, size_t ws_size,
                              hipStream_t stream) {
    const float* X    = (const float*)d_in[0];
    const float* ew   = (const float*)d_in[1];
    const float* eb   = (const float*)d_in[2];
    const float* pw   = (const float*)d_in[3];
    const float* pb   = (const float*)d_in[4];
    const float* keys = (const float*)d_in[5];
    const float* thr  = (const float*)d_in[6];
    const float* fw   = (const float*)d_in[7];
    const float* fb   = (const float*)d_in[8];
    const float* lw   = (const float*)d_in[9];
    const float* lb   = (const float*)d_in[10];
    float* out = (float*)d_out;
    float* Sy  = (float*)d_ws;                                    // 8192 floats (SyT[16][32][16])
    unsigned short* Bg = (unsigned short*)((float*)d_ws + 8192);  // 72*32 bf16
    float* cbf = (float*)d_ws + 9344;                             // 80 bias floats

    prep_kernel<<<1, 256, 0, stream>>>(ew, eb, pw, pb, keys, Sy, Bg, cbf);
    fused_kernel<<<2048, 256, 0, stream>>>(X, Bg, thr, cbf, Sy);
    head_kernel<<<dim3(4, 32), 256, 0, stream>>>(Sy, fw, fb, lw, lb, out);
}

// Round 5
// 37.695 us; speedup vs baseline: 2.5629x; 1.0389x over previous
//
#include <hip/hip_runtime.h>
#include <hip/hip_bf16.h>
#include <math.h>

// X: [32,3,256,256]; 8192 independent 16x16 patches (conv pad=1 zero-pads per
// patch). One wave = one patch, ZERO block-level syncs in the fused kernel.
//
// v6 = v5 + packed-f32 relu/accumulate + XCD-aware block swizzle.
//  - relu+accumulate now runs on f32x2 via v_pk_max_f32/v_pk_add_f32/
//    v_pk_fma_f32 (elementwise builtins): 32 -> 16 VALU per lean step.
//  - block swizzle (wgid&7)*256 + wgid>>3 puts each image's 64 blocks on one
//    XCD: its 16 SyT atomic lines + 768KB of X stay in one L2.
// v5 carried: transposed SyT[cell][b][16] (one 64B line per (cell,b), atomics
// coalesced across the 8 c-lanes). v2 carried: pre-packed bf16 PAIR slabs
// (p2 = pack(v,v+1), px18 = pack(v,v+18)); B k''-slot order matches; hot loop
// = 4 aligned ds_read_b32 -> 5 MFMAs; bias in MFMA C operands; router
// accumulator chained through C.

typedef short bf16x8 __attribute__((ext_vector_type(8)));
typedef float f32x4 __attribute__((ext_vector_type(4)));
typedef float pf2 __attribute__((ext_vector_type(2)));

__device__ __forceinline__ int cellOf(int r) {
    int rr = r + 4;   // padded coordinate; cells of 66 in [0,264)
    return (rr >= 66) + (rr >= 132) + (rr >= 198);
}

__device__ __forceinline__ unsigned int packbf2(float lo, float hi) {
    __hip_bfloat162 h = __float22bfloat162_rn(make_float2(lo, hi));
    unsigned int u;
    __builtin_memcpy(&u, &h, 4);
    return u;
}

// ---------------- prep: zero SyT + build packed B + bias vectors ----------------
__global__ __launch_bounds__(256) void prep_kernel(
    const float* __restrict__ ew, const float* __restrict__ ebg,
    const float* __restrict__ pw, const float* __restrict__ pb,
    const float* __restrict__ keys, float* __restrict__ Sy,
    unsigned short* __restrict__ Bg, float* __restrict__ cbf)
{
    const int t = threadIdx.x;
    for (int i = t; i < 8192; i += 256) Sy[i] = 0.f;
    if (t < 72) {
        float sv[32];
        #pragma unroll
        for (int s = 0; s < 32; ++s) {
            int q, kx; bool zz = false;
            if (s < 16)       { q = s >> 1;  kx = s & 1; }
            else if (s < 18)  { q = 8;       kx = s - 16; }
            else if (s < 26)  { q = s - 18;  kx = 2; }
            else if (s == 26) { q = 8;       kx = 2; }
            else              { q = 0; kx = 0; zz = true; }
            const int ky = q / 3, c = q - ky * 3;
            const int widx = c * 9 + ky * 3 + kx;
            float a;
            if (t < 64) {
                a = ew[t * 27 + widx];
            } else {
                const int e = t - 64;
                a = 0.f;
                #pragma unroll
                for (int o = 0; o < 16; ++o)
                    a += keys[e * 16 + o] * pw[o * 27 + widx];
            }
            sv[s] = zz ? 0.f : a;
        }
        uint4 q0, q1, q2v, q3v;
        q0.x  = packbf2(sv[0],  sv[1]);  q0.y  = packbf2(sv[2],  sv[3]);
        q0.z  = packbf2(sv[4],  sv[5]);  q0.w  = packbf2(sv[6],  sv[7]);
        q1.x  = packbf2(sv[8],  sv[9]);  q1.y  = packbf2(sv[10], sv[11]);
        q1.z  = packbf2(sv[12], sv[13]); q1.w  = packbf2(sv[14], sv[15]);
        q2v.x = packbf2(sv[16], sv[17]); q2v.y = packbf2(sv[18], sv[19]);
        q2v.z = packbf2(sv[20], sv[21]); q2v.w = packbf2(sv[22], sv[23]);
        q3v.x = packbf2(sv[24], sv[25]); q3v.y = packbf2(sv[26], sv[27]);
        q3v.z = packbf2(sv[28], sv[29]); q3v.w = packbf2(sv[30], sv[31]);
        uint4* dst = reinterpret_cast<uint4*>(&Bg[t * 32]);
        dst[0] = q0; dst[1] = q1; dst[2] = q2v; dst[3] = q3v;
    }
    // bias vectors: cbf[0..63] = expert bias per channel; cbf[64..79] = router
    // bias per column (col j -> expert j&7)
    if (t >= 128 && t < 208) {
        const int i = t - 128;
        float c;
        if (i < 64) {
            c = ebg[i];
        } else {
            const int e = (i - 64) & 7;
            c = 0.f;
            #pragma unroll
            for (int o = 0; o < 16; ++o) c += keys[e * 16 + o] * pb[o];
        }
        cbf[i] = c;
    }
}

// one conv step: 4 aligned b32 pair-reads, 5 MFMAs, PACKED relu accumulate.
// pall2[n] (f32x2) accumulates relu over regs; psb2[n] adds jmask-weighted
// (jm2lo = {jmask0,jmask1}, jm2hi = {jmask2,jmask3}); pk_fma via contraction.
#define CONV_STEP(SB, ACCJ) do {                                            \
    uint4 pkv;                                                              \
    pkv.x = pkw[offp0 + (SB)];                                              \
    pkv.y = pkw[offp1 + (SB)];                                              \
    pkv.z = pkw[offp2 + (SB)];                                              \
    pkv.w = pkw[offp3 + (SB)];                                              \
    const bf16x8 afr = __builtin_bit_cast(bf16x8, pkv);                     \
    const f32x4 a0 = __builtin_amdgcn_mfma_f32_16x16x32_bf16(afr, bfr0, cbv0, 0, 0, 0); \
    const f32x4 a1 = __builtin_amdgcn_mfma_f32_16x16x32_bf16(afr, bfr1, cbv1, 0, 0, 0); \
    const f32x4 a2 = __builtin_amdgcn_mfma_f32_16x16x32_bf16(afr, bfr2, cbv2, 0, 0, 0); \
    const f32x4 a3 = __builtin_amdgcn_mfma_f32_16x16x32_bf16(afr, bfr3, cbv3, 0, 0, 0); \
    a4acc = __builtin_amdgcn_mfma_f32_16x16x32_bf16(afr, bfr4, a4acc, 0, 0, 0); \
    const pf2 z2_ = {0.f, 0.f};                                             \
    {                                                                       \
        const pf2 l_ = __builtin_elementwise_max((pf2)__builtin_shufflevector(a0, a0, 0, 1), z2_); \
        const pf2 h_ = __builtin_elementwise_max((pf2)__builtin_shufflevector(a0, a0, 2, 3), z2_); \
        pall2[0] += l_ + h_;                                                \
        if (ACCJ) psb2[0] += l_ * jm2lo + h_ * jm2hi;                       \
    }                                                                       \
    {                                                                       \
        const pf2 l_ = __builtin_elementwise_max((pf2)__builtin_shufflevector(a1, a1, 0, 1), z2_); \
        const pf2 h_ = __builtin_elementwise_max((pf2)__builtin_shufflevector(a1, a1, 2, 3), z2_); \
        pall2[1] += l_ + h_;                                                \
        if (ACCJ) psb2[1] += l_ * jm2lo + h_ * jm2hi;                       \
    }                                                                       \
    {                                                                       \
        const pf2 l_ = __builtin_elementwise_max((pf2)__builtin_shufflevector(a2, a2, 0, 1), z2_); \
        const pf2 h_ = __builtin_elementwise_max((pf2)__builtin_shufflevector(a2, a2, 2, 3), z2_); \
        pall2[2] += l_ + h_;                                                \
        if (ACCJ) psb2[2] += l_ * jm2lo + h_ * jm2hi;                       \
    }                                                                       \
    {                                                                       \
        const pf2 l_ = __builtin_elementwise_max((pf2)__builtin_shufflevector(a3, a3, 0, 1), z2_); \
        const pf2 h_ = __builtin_elementwise_max((pf2)__builtin_shufflevector(a3, a3, 2, 3), z2_); \
        pall2[3] += l_ + h_;                                                \
        if (ACCJ) psb2[3] += l_ * jm2lo + h_ * jm2hi;                       \
    }                                                                       \
} while (0)

// softmax + gate (all 64 lanes; lane's expert e = lid&7)
#define GATES_FROM_RSUM()                                                   \
    rsum += __shfl_xor(rsum, 16);                                           \
    rsum += __shfl_xor(rsum, 32);                                           \
    float gv[4];                                                            \
    {                                                                       \
        float lg = rsum * (1.f / 256.f);                                    \
        float mx = fmaxf(lg, __shfl_xor(lg, 1));                            \
        mx = fmaxf(mx, __shfl_xor(mx, 2));                                  \
        mx = fmaxf(mx, __shfl_xor(mx, 4));                                  \
        float ex = __expf(lg - mx);                                         \
        float s = ex;                                                       \
        s += __shfl_xor(s, 1); s += __shfl_xor(s, 2); s += __shfl_xor(s, 4);\
        float sc = ex / s;                                                  \
        float g = sc / (1.f + __expf(-(sc - thr) * 10.f));                  \
        float gs = g;                                                       \
        gs += __shfl_xor(gs, 1); gs += __shfl_xor(gs, 2); gs += __shfl_xor(gs, 4); \
        float gn = g / (gs + 1e-9f);                                        \
        const int gb = (lid & 56);                                          \
        const int hb = (lid >> 3) & 1;                                      \
        gv[0] = __shfl(gn, gb | (0 + hb));                                  \
        gv[1] = __shfl(gn, gb | (2 + hb));                                  \
        gv[2] = __shfl(gn, gb | (4 + hb));                                  \
        gv[3] = __shfl(gn, gb | (6 + hb));                                  \
    }

// ---------------- fused expert+router conv + cell reduce ----------------
__global__ __launch_bounds__(256, 4) void fused_kernel(
    const float* __restrict__ X, const unsigned short* __restrict__ Bg,
    const float* __restrict__ thr_p, const float* __restrict__ cbf,
    float* __restrict__ Sy)
{
    // per-wave packed pair slabs: p2 at [0..976), px18 stored at 976+i
    __shared__ __align__(16) unsigned int pk[4][1952];

    const int t = threadIdx.x;
    const int wid = t >> 6, lid = t & 63;
    const int r16 = lid & 15, kb = lid >> 4;

    // XCD swizzle: all 64 blocks of one image land on one XCD (2048%8==0)
    const int wgid = blockIdx.x;
    const int virt = (wgid & 7) * 256 + (wgid >> 3);

    const int gp = (virt << 2) + wid;             // patch id 0..8191
    const int b = gp >> 8;
    const int pi = (gp >> 4) & 15, pj = gp & 15;
    const int rbase = pi << 4, cbase = pj << 4;

    unsigned int* pkw = pk[wid];
    const float thr = thr_p[0];

    // ---- issue all global loads up front (in flight together) ----
    const int lr = lid >> 2, lq = lid & 3;
    const float* xb = X + ((b * 3) << 16) + ((rbase + lr) << 8) + cbase + (lq << 2);
    const float4 xv0 = *reinterpret_cast<const float4*>(xb);
    const float4 xv1 = *reinterpret_cast<const float4*>(xb + 65536);
    const float4 xv2 = *reinterpret_cast<const float4*>(xb + 131072);

    const bf16x8 bfr0 = *reinterpret_cast<const bf16x8*>(&Bg[(r16) * 32 + (kb << 3)]);
    const bf16x8 bfr1 = *reinterpret_cast<const bf16x8*>(&Bg[(16 + r16) * 32 + (kb << 3)]);
    const bf16x8 bfr2 = *reinterpret_cast<const bf16x8*>(&Bg[(32 + r16) * 32 + (kb << 3)]);
    const bf16x8 bfr3 = *reinterpret_cast<const bf16x8*>(&Bg[(48 + r16) * 32 + (kb << 3)]);
    const bf16x8 bfr4 = *reinterpret_cast<const bf16x8*>(&Bg[(64 + (r16 & 7)) * 32 + (kb << 3)]);

    const float cbs0 = cbf[r16];
    const float cbs1 = cbf[16 + r16];
    const float cbs2 = cbf[32 + r16];
    const float cbs3 = cbf[48 + r16];
    const float cbs4 = cbf[64 + r16];

    // ---- zero the packed region (covers halo rows/cols; wave-private) ----
    {
        uint4* pk4 = reinterpret_cast<uint4*>(pkw);
        const uint4 z = make_uint4(0u, 0u, 0u, 0u);
        #pragma unroll
        for (int i = 0; i < 8; ++i) {
            const int idx = lid + (i << 6);
            if (idx < 488) pk4[idx] = z;
        }
    }
    __builtin_amdgcn_wave_barrier();

    // ---- build packed pair slabs straight from registers ----
    // lane owns input row lr (slab y = lr+1), slab cols 4lq+1..4lq+4, 3 chans.
    float s0 = __shfl_up(xv0.w, 1);
    float s1 = __shfl_up(xv1.w, 1);
    float s2 = __shfl_up(xv2.w, 1);
    const float c0p = (lq == 0) ? 0.f : s0;   // col 4lq (left neighbor / halo)
    const float c1p = (lq == 0) ? 0.f : s1;
    const float c2p = (lq == 0) ? 0.f : s2;
    float nxx = __shfl_down(xv0.x, 4);        // next row, channel 0 (for px c2)
    float nxy = __shfl_down(xv0.y, 4);
    float nxz = __shfl_down(xv0.z, 4);
    float nxw = __shfl_down(xv0.w, 4);
    if (lr == 15) { nxx = 0.f; nxy = 0.f; nxz = 0.f; nxw = 0.f; }

    {
        const int y = lr + 1;
        const int b2 = y * 54 + (lq << 2);            // p2: pairs (col p, col p+1)
        unsigned int u0, u1, u2, u3;
        u0 = packbf2(c0p,   xv0.x); u1 = packbf2(xv0.x, xv0.y);
        u2 = packbf2(xv0.y, xv0.z); u3 = packbf2(xv0.z, xv0.w);
        *reinterpret_cast<uint2*>(&pkw[b2])      = make_uint2(u0, u1);
        *reinterpret_cast<uint2*>(&pkw[b2 + 2])  = make_uint2(u2, u3);
        u0 = packbf2(c1p,   xv1.x); u1 = packbf2(xv1.x, xv1.y);
        u2 = packbf2(xv1.y, xv1.z); u3 = packbf2(xv1.z, xv1.w);
        *reinterpret_cast<uint2*>(&pkw[b2 + 18]) = make_uint2(u0, u1);
        *reinterpret_cast<uint2*>(&pkw[b2 + 20]) = make_uint2(u2, u3);
        u0 = packbf2(c2p,   xv2.x); u1 = packbf2(xv2.x, xv2.y);
        u2 = packbf2(xv2.y, xv2.z); u3 = packbf2(xv2.z, xv2.w);
        *reinterpret_cast<uint2*>(&pkw[b2 + 36]) = make_uint2(u0, u1);
        *reinterpret_cast<uint2*>(&pkw[b2 + 38]) = make_uint2(u2, u3);

        const int bx = 976 + y * 54 + (lq << 2);      // px18: pairs (stripe, stripe+18)
        u0 = packbf2(xv0.x, xv1.x); u1 = packbf2(xv0.y, xv1.y);
        u2 = packbf2(xv0.z, xv1.z); u3 = packbf2(xv0.w, xv1.w);
        *reinterpret_cast<uint2*>(&pkw[bx])      = make_uint2(u0, u1);
        *reinterpret_cast<uint2*>(&pkw[bx + 2])  = make_uint2(u2, u3);
        u0 = packbf2(xv1.x, xv2.x); u1 = packbf2(xv1.y, xv2.y);
        u2 = packbf2(xv1.z, xv2.z); u3 = packbf2(xv1.w, xv2.w);
        *reinterpret_cast<uint2*>(&pkw[bx + 18]) = make_uint2(u0, u1);
        *reinterpret_cast<uint2*>(&pkw[bx + 20]) = make_uint2(u2, u3);
        u0 = packbf2(xv2.x, nxx);  u1 = packbf2(xv2.y, nxy);
        u2 = packbf2(xv2.z, nxz);  u3 = packbf2(xv2.w, nxw);
        *reinterpret_cast<uint2*>(&pkw[bx + 36]) = make_uint2(u0, u1);
        *reinterpret_cast<uint2*>(&pkw[bx + 38]) = make_uint2(u2, u3);

        if (lr == 0) {  // px18 halo row 0, c2 stripe pairs with real row-1 c0
            const int b0 = 976 + 36 + (lq << 2);
            u0 = packbf2(0.f, xv0.x); u1 = packbf2(0.f, xv0.y);
            u2 = packbf2(0.f, xv0.z); u3 = packbf2(0.f, xv0.w);
            *reinterpret_cast<uint2*>(&pkw[b0])     = make_uint2(u0, u1);
            *reinterpret_cast<uint2*>(&pkw[b0 + 2]) = make_uint2(u2, u3);
        }
    }
    __builtin_amdgcn_wave_barrier();

    // ---- per-lane pair-read offsets (dwords); +mt*54 in loop, folded to imm ----
    int offp0, offp1, offp2, offp3;
    if (kb < 2) {                       // q0..q7 (kx0,kx1) pairs in p2
        const int t0 = kb * 72 + r16;
        offp0 = t0; offp1 = t0 + 18; offp2 = t0 + 36; offp3 = t0 + 54;
    } else if (kb == 2) {               // q8 pair in p2; q0/q2/q4 kx2 pairs in px18
        offp0 = 144 + r16; offp1 = 977 + r16; offp2 = 1013 + r16; offp3 = 1049 + r16;
    } else {                            // q6,q8 kx2 pairs in px18; slots 28..31 dead
        offp0 = 1085 + r16; offp1 = 1121 + r16; offp2 = 1121 + r16; offp3 = 1121 + r16;
    }

    const f32x4 cbv0 = {cbs0, cbs0, cbs0, cbs0};
    const f32x4 cbv1 = {cbs1, cbs1, cbs1, cbs1};
    const f32x4 cbv2 = {cbs2, cbs2, cbs2, cbs2};
    const f32x4 cbv3 = {cbs3, cbs3, cbs3, cbs3};
    const float rb16 = cbs4 * 16.f;     // router bias: 16 steps fold into C init
    f32x4 a4acc = {rb16, rb16, rb16, rb16};

    // ---- split geometry (wave-uniform) ----
    const int iA = cellOf(rbase), iB = cellOf(rbase + 15);
    const int jA = cellOf(cbase), jB = cellOf(cbase + 15);
    const int isp = (iA + 1) * 66 - 4 - rbase;    // <16 iff i-split
    const int jsp = (jA + 1) * 66 - 4 - cbase;    // <16 iff j-split
    const bool anySplit = (isp < 16) | (jsp < 16);

    const int bc16 = b << 4;            // SyT[cell][b][16]: line-sized groups
    const pf2 zz2 = {0.f, 0.f};

    if (!anySplit) {
        // ================= lean path (75% of patches) =================
        pf2 pall2[4] = {zz2, zz2, zz2, zz2};
        pf2 psb2[4]  = {zz2, zz2, zz2, zz2};      // dead (ACCJ=0)
        pf2 jm2lo = zz2, jm2hi = zz2;             // dead
        #pragma unroll
        for (int mt = 0; mt < 16; ++mt) CONV_STEP(mt * 54, 0);

        float rsum = (a4acc[0] + a4acc[1]) + (a4acc[2] + a4acc[3]);
        GATES_FROM_RSUM();

        float tt = 0.f;
        #pragma unroll
        for (int nt = 0; nt < 4; ++nt)
            tt = fmaf(gv[nt], pall2[nt].x + pall2[nt].y, tt);
        tt += __shfl_xor(tt, 8);
        tt += __shfl_xor(tt, 16);
        tt += __shfl_xor(tt, 32);
        if (lid < 8)
            atomicAdd(&Sy[(iA * 4 + jA) * 512 + bc16 + lid], tt);
    } else {
        // ================= generic split path =================
        float jmask[4];
        #pragma unroll
        for (int r = 0; r < 4; ++r)
            jmask[r] = ((kb << 2) + r >= jsp) ? 1.f : 0.f;
        const pf2 jm2lo = {jmask[0], jmask[1]};
        const pf2 jm2hi = {jmask[2], jmask[3]};

        pf2 pall2[4] = {zz2, zz2, zz2, zz2};
        pf2 psb2[4]  = {zz2, zz2, zz2, zz2};
        const int m1 = isp < 16 ? isp : 16;

        int sb = 0;
        for (int mt = 0; mt < m1; ++mt) { CONV_STEP(sb, 1); sb += 54; }
        const float pa0_0 = pall2[0].x + pall2[0].y;
        const float pa0_1 = pall2[1].x + pall2[1].y;
        const float pa0_2 = pall2[2].x + pall2[2].y;
        const float pa0_3 = pall2[3].x + pall2[3].y;
        const float pb0_0 = psb2[0].x + psb2[0].y;
        const float pb0_1 = psb2[1].x + psb2[1].y;
        const float pb0_2 = psb2[2].x + psb2[2].y;
        const float pb0_3 = psb2[3].x + psb2[3].y;
        pall2[0] = pall2[1] = pall2[2] = pall2[3] = zz2;
        psb2[0] = psb2[1] = psb2[2] = psb2[3] = zz2;
        for (int mt = m1; mt < 16; ++mt) { CONV_STEP(sb, 1); sb += 54; }

        float rsum = (a4acc[0] + a4acc[1]) + (a4acc[2] + a4acc[3]);
        GATES_FROM_RSUM();

        float tTA = gv[0] * pa0_0 + gv[1] * pa0_1 + gv[2] * pa0_2 + gv[3] * pa0_3;
        float tTB = gv[0] * pb0_0 + gv[1] * pb0_1 + gv[2] * pb0_2 + gv[3] * pb0_3;
        float tBA = 0.f, tBB = 0.f;
        #pragma unroll
        for (int nt = 0; nt < 4; ++nt) {
            tBA = fmaf(gv[nt], pall2[nt].x + pall2[nt].y, tBA);
            tBB = fmaf(gv[nt], psb2[nt].x + psb2[nt].y, tBB);
        }
        #pragma unroll
        for (int m = 8; m <= 32; m <<= 1) {
            tTA += __shfl_xor(tTA, m);
            tTB += __shfl_xor(tTB, m);
            tBA += __shfl_xor(tBA, m);
            tBB += __shfl_xor(tBB, m);
        }
        if (lid < 8) {
            atomicAdd(&Sy[(iA * 4 + jA) * 512 + bc16 + lid], tTA - tTB);
            atomicAdd(&Sy[(iA * 4 + jB) * 512 + bc16 + lid], tTB);
            atomicAdd(&Sy[(iB * 4 + jA) * 512 + bc16 + lid], tBA - tBB);
            atomicAdd(&Sy[(iB * 4 + jB) * 512 + bc16 + lid], tBB);
        }
    }
}

// ---------------- SPP + head ----------------
__global__ __launch_bounds__(256) void head_kernel(
    const float* __restrict__ Sy, const float* __restrict__ fw,
    const float* __restrict__ fb, const float* __restrict__ lw,
    const float* __restrict__ lb, float* __restrict__ out)
{
    __shared__ float syl[128];
    __shared__ float s2[32];
    __shared__ float stot[8];
    __shared__ float spp[168];
    const int t = threadIdx.x;
    const int b = blockIdx.y;
    // SyT[cell][b][16]: syl[c*16+cell] = SyT[cell*512 + b*16 + c]
    if (t < 128) syl[t] = Sy[(t & 15) * 512 + b * 16 + (t >> 4)];
    __syncthreads();
    if (t < 32) {
        int c = t >> 2, I = (t >> 1) & 1, J = t & 1;
        const float* p = &syl[c * 16];
        s2[t] = p[(2 * I) * 4 + 2 * J] + p[(2 * I) * 4 + 2 * J + 1] +
                p[(2 * I + 1) * 4 + 2 * J] + p[(2 * I + 1) * 4 + 2 * J + 1];
    } else if (t >= 32 && t < 40) {
        int c = t - 32;
        float s = 0.f;
        #pragma unroll
        for (int i2 = 0; i2 < 16; ++i2) s += syl[c * 16 + i2];
        stot[c] = s;
    }
    __syncthreads();
    if (t < 168) {
        float acc = 0.f;
        int o;
        if (t < 8) {
            o = t;
            #pragma unroll
            for (int c = 0; c < 8; ++c) acc += fw[o * 8 + c] * stot[c];
            acc *= (1.f / 69696.f);
        } else if (t < 40) {
            int m = t - 8; o = m >> 2; int q = m & 3;
            #pragma unroll
            for (int c = 0; c < 8; ++c) acc += fw[o * 8 + c] * s2[c * 4 + q];
            acc *= (1.f / 17424.f);
        } else {
            int m = t - 40; o = m >> 4; int cell = m & 15;
            #pragma unroll
            for (int c = 0; c < 8; ++c) acc += fw[o * 8 + c] * syl[c * 16 + cell];
            acc *= (1.f / 4356.f);
        }
        spp[t] = acc + fb[o];
    }
    __syncthreads();
    const int n = blockIdx.x * 256 + t;
    if (n < 1000) {
        float acc = lb[n];
        for (int k = 0; k < 168; ++k) acc = fmaf(spp[k], lw[k * 1000 + n], acc);
        out[b * 1000 + n] = acc;
    }
}

extern "C" void kernel_launch(void* const* d_in, const int* in_sizes, int n_in,
                              void* d_out, int out_size, void* d_ws, size_t ws_size,
                              hipStream_t stream) {
    const float* X    = (const float*)d_in[0];
    const float* ew   = (const float*)d_in[1];
    const float* eb   = (const float*)d_in[2];
    const float* pw   = (const float*)d_in[3];
    const float* pb   = (const float*)d_in[4];
    const float* keys = (const float*)d_in[5];
    const float* thr  = (const float*)d_in[6];
    const float* fw   = (const float*)d_in[7];
    const float* fb   = (const float*)d_in[8];
    const float* lw   = (const float*)d_in[9];
    const float* lb   = (const float*)d_in[10];
    float* out = (float*)d_out;
    float* Sy  = (float*)d_ws;                                    // 8192 floats (SyT[16][32][16])
    unsigned short* Bg = (unsigned short*)((float*)d_ws + 8192);  // 72*32 bf16
    float* cbf = (float*)d_ws + 9344;                             // 80 bias floats

    prep_kernel<<<1, 256, 0, stream>>>(ew, eb, pw, pb, keys, Sy, Bg, cbf);
    fused_kernel<<<2048, 256, 0, stream>>>(X, Bg, thr, cbf, Sy);
    head_kernel<<<dim3(4, 32), 256, 0, stream>>>(Sy, fw, fb, lw, lb, out);
}